// Round 1
// baseline (529.152 us; speedup 1.0000x reference)
//
#include <hip/hip_runtime.h>

// DiceCoeffMetric: per-(b,c) {dot(prd,tgt), sum(prd), sum(tgt)} over 1024x1024,
// dice = (2*inter+eps)/(sum_p+sum_t+eps), then mean over batch -> (C,) fp32.
// Memory-bound: 512 MB read -> ~85us floor at 6.3 TB/s.

#define HW   (1024 * 1024)
#define NB   16
#define NC   4
#define NBC  (NB * NC)      // 64 (b,c) slices
#define BPS  64             // blocks per slice
#define TPB  256
#define EPSF 1e-6f

__global__ void zero_ws_kernel(float* __restrict__ ws) {
    int i = threadIdx.x;
    if (i < NBC * 3) ws[i] = 0.0f;
}

__global__ __launch_bounds__(TPB) void dice_partial_kernel(
        const float* __restrict__ prd,
        const float* __restrict__ tgt,
        float* __restrict__ ws) {
    const int bc = blockIdx.y;
    const float4* __restrict__ p4 = (const float4*)(prd + (size_t)bc * HW);
    const float4* __restrict__ t4 = (const float4*)(tgt + (size_t)bc * HW);
    const int n4 = HW / 4;  // 262144 float4 per slice

    float inter = 0.0f, sp = 0.0f, st = 0.0f;
    for (int i = blockIdx.x * TPB + threadIdx.x; i < n4; i += BPS * TPB) {
        float4 a = p4[i];
        float4 b = t4[i];
        inter += a.x * b.x + a.y * b.y + a.z * b.z + a.w * b.w;
        sp    += a.x + a.y + a.z + a.w;
        st    += b.x + b.y + b.z + b.w;
    }

    // wave-64 butterfly-ish reduce (shfl_down over full 64-lane wave)
    #pragma unroll
    for (int off = 32; off > 0; off >>= 1) {
        inter += __shfl_down(inter, off);
        sp    += __shfl_down(sp, off);
        st    += __shfl_down(st, off);
    }

    __shared__ float s[3][TPB / 64];
    const int wave = threadIdx.x >> 6;
    const int lane = threadIdx.x & 63;
    if (lane == 0) {
        s[0][wave] = inter;
        s[1][wave] = sp;
        s[2][wave] = st;
    }
    __syncthreads();
    if (threadIdx.x == 0) {
        float ti = s[0][0] + s[0][1] + s[0][2] + s[0][3];
        float tp = s[1][0] + s[1][1] + s[1][2] + s[1][3];
        float tt = s[2][0] + s[2][1] + s[2][2] + s[2][3];
        atomicAdd(&ws[bc * 3 + 0], ti);
        atomicAdd(&ws[bc * 3 + 1], tp);
        atomicAdd(&ws[bc * 3 + 2], tt);
    }
}

__global__ void dice_final_kernel(const float* __restrict__ ws,
                                  float* __restrict__ out) {
    __shared__ float dice[NBC];
    const int bc = threadIdx.x;
    if (bc < NBC) {
        float inter = ws[bc * 3 + 0];
        float uni   = ws[bc * 3 + 1] + ws[bc * 3 + 2] + EPSF;
        dice[bc] = (2.0f * inter + EPSF) / uni;
    }
    __syncthreads();
    if (bc < NC) {
        float s = 0.0f;
        #pragma unroll
        for (int b = 0; b < NB; ++b) s += dice[b * NC + bc];
        out[bc] = s / (float)NB;
    }
}

extern "C" void kernel_launch(void* const* d_in, const int* in_sizes, int n_in,
                              void* d_out, int out_size, void* d_ws, size_t ws_size,
                              hipStream_t stream) {
    const float* prd = (const float*)d_in[0];
    const float* tgt = (const float*)d_in[1];
    float* out = (float*)d_out;
    float* ws  = (float*)d_ws;   // 64 * 3 floats of accumulators

    zero_ws_kernel<<<1, 256, 0, stream>>>(ws);
    dice_partial_kernel<<<dim3(BPS, NBC), TPB, 0, stream>>>(prd, tgt, ws);
    dice_final_kernel<<<1, 64, 0, stream>>>(ws, out);
}

// Round 2
// 473.847 us; speedup vs baseline: 1.1167x; 1.1167x over previous
//
#include <hip/hip_runtime.h>

// DiceCoeffMetric: per-(b,c) {dot(prd,tgt), sum(prd), sum(tgt)} over 1024x1024 fp32,
// dice = (2*inter+eps)/(sum_p+sum_t+eps), mean over batch -> (C,) fp32.
// Memory-bound: 512 MB read -> ~85us floor at 6.3 TB/s.
// R2: hand-unrolled x4 (8 loads in flight/wave), nontemporal loads,
//     per-block partial slots instead of atomics (drops zero kernel).

#define HW   (1024 * 1024)
#define NB   16
#define NC   4
#define NBC  (NB * NC)      // 64 (b,c) slices
#define BPS  64             // blocks per slice
#define TPB  256
#define NBLK (NBC * BPS)    // 4096 partial slots
#define EPSF 1e-6f

typedef float vf4 __attribute__((ext_vector_type(4)));

__global__ __launch_bounds__(TPB) void dice_partial_kernel(
        const float* __restrict__ prd,
        const float* __restrict__ tgt,
        float* __restrict__ ws) {
    const int bc = blockIdx.y;
    const vf4* __restrict__ p4 = (const vf4*)(prd + (size_t)bc * HW);
    const vf4* __restrict__ t4 = (const vf4*)(tgt + (size_t)bc * HW);

    const int S   = BPS * TPB;                      // 16384 float4 stride
    const int tid = blockIdx.x * TPB + threadIdx.x; // 0..16383

    float inter = 0.0f, sp = 0.0f, st = 0.0f;

    // 262144 float4 per slice / 16384 = 16 iterations; unroll 4x4.
    #pragma unroll
    for (int g = 0; g < 4; ++g) {
        const int i = tid + g * 4 * S;
        vf4 a0 = __builtin_nontemporal_load(p4 + i);
        vf4 a1 = __builtin_nontemporal_load(p4 + i + S);
        vf4 a2 = __builtin_nontemporal_load(p4 + i + 2 * S);
        vf4 a3 = __builtin_nontemporal_load(p4 + i + 3 * S);
        vf4 b0 = __builtin_nontemporal_load(t4 + i);
        vf4 b1 = __builtin_nontemporal_load(t4 + i + S);
        vf4 b2 = __builtin_nontemporal_load(t4 + i + 2 * S);
        vf4 b3 = __builtin_nontemporal_load(t4 + i + 3 * S);

        inter += a0.x * b0.x + a0.y * b0.y + a0.z * b0.z + a0.w * b0.w;
        inter += a1.x * b1.x + a1.y * b1.y + a1.z * b1.z + a1.w * b1.w;
        inter += a2.x * b2.x + a2.y * b2.y + a2.z * b2.z + a2.w * b2.w;
        inter += a3.x * b3.x + a3.y * b3.y + a3.z * b3.z + a3.w * b3.w;
        sp += (a0.x + a0.y + a0.z + a0.w) + (a1.x + a1.y + a1.z + a1.w)
            + (a2.x + a2.y + a2.z + a2.w) + (a3.x + a3.y + a3.z + a3.w);
        st += (b0.x + b0.y + b0.z + b0.w) + (b1.x + b1.y + b1.z + b1.w)
            + (b2.x + b2.y + b2.z + b2.w) + (b3.x + b3.y + b3.z + b3.w);
    }

    // wave-64 reduce
    #pragma unroll
    for (int off = 32; off > 0; off >>= 1) {
        inter += __shfl_down(inter, off);
        sp    += __shfl_down(sp, off);
        st    += __shfl_down(st, off);
    }

    __shared__ float s[3][TPB / 64];
    const int wave = threadIdx.x >> 6;
    const int lane = threadIdx.x & 63;
    if (lane == 0) {
        s[0][wave] = inter;
        s[1][wave] = sp;
        s[2][wave] = st;
    }
    __syncthreads();
    if (threadIdx.x == 0) {
        const int slot = bc * BPS + blockIdx.x;   // unique per block
        ws[0 * NBLK + slot] = s[0][0] + s[0][1] + s[0][2] + s[0][3];
        ws[1 * NBLK + slot] = s[1][0] + s[1][1] + s[1][2] + s[1][3];
        ws[2 * NBLK + slot] = s[2][0] + s[2][1] + s[2][2] + s[2][3];
    }
}

__global__ void dice_final_kernel(const float* __restrict__ ws,
                                  float* __restrict__ out) {
    __shared__ float dice[NBC];
    const int bc = threadIdx.x;
    if (bc < NBC) {
        float inter = 0.0f, sp = 0.0f, st = 0.0f;
        #pragma unroll 8
        for (int k = 0; k < BPS; ++k) {
            const int slot = bc * BPS + k;
            inter += ws[0 * NBLK + slot];
            sp    += ws[1 * NBLK + slot];
            st    += ws[2 * NBLK + slot];
        }
        dice[bc] = (2.0f * inter + EPSF) / (sp + st + EPSF);
    }
    __syncthreads();
    if (bc < NC) {
        float s = 0.0f;
        #pragma unroll
        for (int b = 0; b < NB; ++b) s += dice[b * NC + bc];
        out[bc] = s / (float)NB;
    }
}

extern "C" void kernel_launch(void* const* d_in, const int* in_sizes, int n_in,
                              void* d_out, int out_size, void* d_ws, size_t ws_size,
                              hipStream_t stream) {
    const float* prd = (const float*)d_in[0];
    const float* tgt = (const float*)d_in[1];
    float* out = (float*)d_out;
    float* ws  = (float*)d_ws;   // 3 * 4096 floats of per-block partials

    dice_partial_kernel<<<dim3(BPS, NBC), TPB, 0, stream>>>(prd, tgt, ws);
    dice_final_kernel<<<1, 64, 0, stream>>>(ws, out);
}

// Round 4
// 469.506 us; speedup vs baseline: 1.1270x; 1.0092x over previous
//
#include <hip/hip_runtime.h>

// DiceCoeffMetric: per-(b,c) {dot(prd,tgt), sum(prd), sum(tgt)} over 1024x1024 fp32,
// dice = (2*inter+eps)/(sum_p+sum_t+eps), mean over batch -> (C,) fp32.
// Memory-bound: 512 MB read. R3 (rerun; R3 bench was an acquisition timeout):
// wave-contiguous streaming (each wave reads contiguous 16KB runs,
// j*1KB + lane*16B) + 16 loads in flight per stage.

#define HW   (1024 * 1024)
#define NB   16
#define NC   4
#define NBC  (NB * NC)      // 64 (b,c) slices
#define BPS  64             // blocks per slice
#define TPB  256
#define NBLK (NBC * BPS)    // 4096 partial slots
#define EPSF 1e-6f

typedef float vf4 __attribute__((ext_vector_type(4)));

#define DOT4(a, b)  ((a).x * (b).x + (a).y * (b).y + (a).z * (b).z + (a).w * (b).w)
#define SUM4(a)     ((a).x + (a).y + (a).z + (a).w)

__global__ __launch_bounds__(TPB) void dice_partial_kernel(
        const float* __restrict__ prd,
        const float* __restrict__ tgt,
        float* __restrict__ ws) {
    const int bc   = blockIdx.y;
    const int wave = threadIdx.x >> 6;
    const int lane = threadIdx.x & 63;

    // slice = 262144 float4; block = 4096 float4 (64KB); wave = 1024 float4 (16KB)
    const size_t base = (size_t)bc * (HW / 4) + (size_t)blockIdx.x * 4096
                      + (size_t)wave * 1024 + lane;
    const vf4* __restrict__ p4 = (const vf4*)prd + base;
    const vf4* __restrict__ t4 = (const vf4*)tgt + base;

    float i0 = 0.0f, i1 = 0.0f, sp0 = 0.0f, sp1 = 0.0f, st0 = 0.0f, st1 = 0.0f;

    // 16 float4 per thread: two stages of 8+8 loads (16KB/wave in flight/stage).
    #pragma unroll
    for (int h = 0; h < 2; ++h) {
        const int o = h * 512;   // 8 runs of 64 float4 each
        vf4 a0 = __builtin_nontemporal_load(p4 + o);
        vf4 a1 = __builtin_nontemporal_load(p4 + o + 64);
        vf4 a2 = __builtin_nontemporal_load(p4 + o + 128);
        vf4 a3 = __builtin_nontemporal_load(p4 + o + 192);
        vf4 a4 = __builtin_nontemporal_load(p4 + o + 256);
        vf4 a5 = __builtin_nontemporal_load(p4 + o + 320);
        vf4 a6 = __builtin_nontemporal_load(p4 + o + 384);
        vf4 a7 = __builtin_nontemporal_load(p4 + o + 448);
        vf4 b0 = __builtin_nontemporal_load(t4 + o);
        vf4 b1 = __builtin_nontemporal_load(t4 + o + 64);
        vf4 b2 = __builtin_nontemporal_load(t4 + o + 128);
        vf4 b3 = __builtin_nontemporal_load(t4 + o + 192);
        vf4 b4 = __builtin_nontemporal_load(t4 + o + 256);
        vf4 b5 = __builtin_nontemporal_load(t4 + o + 320);
        vf4 b6 = __builtin_nontemporal_load(t4 + o + 384);
        vf4 b7 = __builtin_nontemporal_load(t4 + o + 448);

        i0  += DOT4(a0, b0) + DOT4(a2, b2) + DOT4(a4, b4) + DOT4(a6, b6);
        i1  += DOT4(a1, b1) + DOT4(a3, b3) + DOT4(a5, b5) + DOT4(a7, b7);
        sp0 += SUM4(a0) + SUM4(a2) + SUM4(a4) + SUM4(a6);
        sp1 += SUM4(a1) + SUM4(a3) + SUM4(a5) + SUM4(a7);
        st0 += SUM4(b0) + SUM4(b2) + SUM4(b4) + SUM4(b6);
        st1 += SUM4(b1) + SUM4(b3) + SUM4(b5) + SUM4(b7);
    }

    float inter = i0 + i1, sp = sp0 + sp1, st = st0 + st1;

    // wave-64 reduce
    #pragma unroll
    for (int off = 32; off > 0; off >>= 1) {
        inter += __shfl_down(inter, off);
        sp    += __shfl_down(sp, off);
        st    += __shfl_down(st, off);
    }

    __shared__ float s[3][TPB / 64];
    if (lane == 0) {
        s[0][wave] = inter;
        s[1][wave] = sp;
        s[2][wave] = st;
    }
    __syncthreads();
    if (threadIdx.x == 0) {
        const int slot = bc * BPS + blockIdx.x;   // unique per block
        ws[0 * NBLK + slot] = s[0][0] + s[0][1] + s[0][2] + s[0][3];
        ws[1 * NBLK + slot] = s[1][0] + s[1][1] + s[1][2] + s[1][3];
        ws[2 * NBLK + slot] = s[2][0] + s[2][1] + s[2][2] + s[2][3];
    }
}

__global__ void dice_final_kernel(const float* __restrict__ ws,
                                  float* __restrict__ out) {
    __shared__ float dice[NBC];
    const int bc = threadIdx.x;
    if (bc < NBC) {
        float inter = 0.0f, sp = 0.0f, st = 0.0f;
        #pragma unroll 8
        for (int k = 0; k < BPS; ++k) {
            const int slot = bc * BPS + k;
            inter += ws[0 * NBLK + slot];
            sp    += ws[1 * NBLK + slot];
            st    += ws[2 * NBLK + slot];
        }
        dice[bc] = (2.0f * inter + EPSF) / (sp + st + EPSF);
    }
    __syncthreads();
    if (bc < NC) {
        float s = 0.0f;
        #pragma unroll
        for (int b = 0; b < NB; ++b) s += dice[b * NC + bc];
        out[bc] = s / (float)NB;
    }
}

extern "C" void kernel_launch(void* const* d_in, const int* in_sizes, int n_in,
                              void* d_out, int out_size, void* d_ws, size_t ws_size,
                              hipStream_t stream) {
    const float* prd = (const float*)d_in[0];
    const float* tgt = (const float*)d_in[1];
    float* out = (float*)d_out;
    float* ws  = (float*)d_ws;   // 3 * 4096 floats of per-block partials

    dice_partial_kernel<<<dim3(BPS, NBC), TPB, 0, stream>>>(prd, tgt, ws);
    dice_final_kernel<<<1, 64, 0, stream>>>(ws, out);
}